// Round 3
// baseline (405.784 us; speedup 1.0000x reference)
//
#include <hip/hip_runtime.h>
#include <math.h>

#define H    4096
#define BB   8
#define NN   200
#define EE   400
#define NT_NF 7          // 7 * 32 = 224 >= 200 padded rows
#define KT16 256         // H/16 k-tiles
#define HT32 128         // H/32 h-tiles
#define KSM8 32          // k-split for M=8 GEMMs

typedef __bf16 bf16x8 __attribute__((ext_vector_type(8)));
typedef float f32x16 __attribute__((ext_vector_type(16)));

// ---------------- ws layout (bytes) ----------------
#define OFF_QH   0u
#define OFF_QL   262144u
#define OFF_AH   524288u
#define OFF_AL   786432u
#define OFF_TH   1048576u
#define OFF_TL   1310720u
#define OFF_NFH  1572864u
#define OFF_NFL  3407872u
#define OFF_QP   5242880u
#define OFF_HB   5373952u
#define OFF_FB   5505024u
#define OFF_KEY  5636096u
#define OFF_META 5642496u
#define OFF_LIST 5643008u
#define OFF_SH   5650432u   // shared region: P8 (4MB) then reused as NPJP

__device__ __forceinline__ unsigned short f2bf(float x) {
  unsigned int u = __float_as_uint(x);
  u = (u + 0x7fffu + ((u >> 16) & 1u)) >> 16;
  return (unsigned short)u;
}
__device__ __forceinline__ float bf2f(unsigned short b) {
  return __uint_as_float(((unsigned int)b) << 16);
}

union U8 { unsigned short s[8]; bf16x8 v; uint4 q; };

// ---------- pack an 8-row f32 matrix into 32x32x16 A-fragment order (hi/lo) ----------
// frag layout: [ktile16][lane 64][8 bf16]; lane: row = l&31, k = ktile*16 + (l>>5)*8
__global__ __launch_bounds__(256) void k_pack8(const float* __restrict__ X,
                                               unsigned short* __restrict__ hi,
                                               unsigned short* __restrict__ lo) {
  int t = blockIdx.x * 256 + threadIdx.x;      // 16384 = 256 kt * 64
  int ktile = t >> 6, lane = t & 63;
  int row = lane & 31;
  int k = ktile * 16 + (lane >> 5) * 8;
  float4 a = make_float4(0.f, 0.f, 0.f, 0.f), b = a;
  if (row < 8) {
    a = *(const float4*)&X[(size_t)row * H + k];
    b = *(const float4*)&X[(size_t)row * H + k + 4];
  }
  float xs[8] = {a.x, a.y, a.z, a.w, b.x, b.y, b.z, b.w};
  U8 hv, lv;
#pragma unroll
  for (int j = 0; j < 8; j++) {
    unsigned short h = f2bf(xs[j]);
    hv.s[j] = h;
    lv.s[j] = f2bf(xs[j] - bf2f(h));
  }
  *(uint4*)&hi[(size_t)t * 8] = hv.q;
  *(uint4*)&lo[(size_t)t * 8] = lv.q;
}

// ---------- pack node_features into fragment order, 7 n-tiles ----------
// frag layout: [ktile16][ntile 7][lane 64][8 bf16]
__global__ __launch_bounds__(256) void k_pack_nf(const float* __restrict__ nf,
                                                 unsigned short* __restrict__ hi,
                                                 unsigned short* __restrict__ lo) {
  int t = blockIdx.x * 256 + threadIdx.x;      // 114688 = 256 * 7 * 64
  int ktile = t / (NT_NF * 64);
  int rem = t - ktile * (NT_NF * 64);
  int ntile = rem >> 6, lane = rem & 63;
  int n = ntile * 32 + (lane & 31);
  int k = ktile * 16 + (lane >> 5) * 8;
  float4 a = make_float4(0.f, 0.f, 0.f, 0.f), b = a;
  if (n < NN) {
    a = *(const float4*)&nf[(size_t)n * H + k];
    b = *(const float4*)&nf[(size_t)n * H + k + 4];
  }
  float xs[8] = {a.x, a.y, a.z, a.w, b.x, b.y, b.z, b.w};
  U8 hv, lv;
#pragma unroll
  for (int j = 0; j < 8; j++) {
    unsigned short h = f2bf(xs[j]);
    hv.s[j] = h;
    lv.s[j] = f2bf(xs[j] - bf2f(h));
  }
  *(uint4*)&hi[(size_t)t * 8] = hv.q;
  *(uint4*)&lo[(size_t)t * 8] = lv.q;
}

// ---------- LDS-free MFMA GEMM: partial[kb][n][h] += frag-A * W^T ----------
// wave gw: htile = gw & 127, kb = gw >> 7; owns 32 h-cols, nk k-tiles, NT n-tiles.
// W converted in-wave to hi/lo bf16; 3-pass split product.
template<int NT, int MINW>
__global__ __launch_bounds__(256, MINW) void k_mfma32(const unsigned short* __restrict__ ahi,
                                                      const unsigned short* __restrict__ alo,
                                                      const float* __restrict__ W,
                                                      float* __restrict__ partial,
                                                      int nk, int nrows) {
  const int gw = (blockIdx.x * 256 + threadIdx.x) >> 6;
  const int lane = threadIdx.x & 63;
  const int htile = gw & (HT32 - 1);
  const int kb = gw >> 7;
  const int h0 = htile * 32;
  const int ktile0 = kb * nk;
  const int l31 = lane & 31, lg = lane >> 5;

  f32x16 acc[NT];
#pragma unroll
  for (int nt = 0; nt < NT; nt++)
#pragma unroll
    for (int i = 0; i < 16; i++) acc[nt][i] = 0.f;

  const float* wbase = W + (size_t)(h0 + l31) * H + lg * 8;

#pragma unroll 2
  for (int ck = 0; ck < nk; ++ck) {
    const int ktile = ktile0 + ck;
    const float4* wp = (const float4*)(wbase + ktile * 16);
    float4 w0 = wp[0], w1 = wp[1];
    float xs[8] = {w0.x, w0.y, w0.z, w0.w, w1.x, w1.y, w1.z, w1.w};
    U8 bh, bl;
#pragma unroll
    for (int j = 0; j < 8; j++) {
      unsigned short hb = f2bf(xs[j]);
      bh.s[j] = hb;
      bl.s[j] = f2bf(xs[j] - bf2f(hb));
    }
#pragma unroll
    for (int nt = 0; nt < NT; nt++) {
      U8 ah, al;
      ah.q = *(const uint4*)&ahi[((size_t)(ktile * NT + nt) * 64 + lane) * 8];
      al.q = *(const uint4*)&alo[((size_t)(ktile * NT + nt) * 64 + lane) * 8];
      acc[nt] = __builtin_amdgcn_mfma_f32_32x32x16_bf16(ah.v, bh.v, acc[nt], 0, 0, 0);
      acc[nt] = __builtin_amdgcn_mfma_f32_32x32x16_bf16(ah.v, bl.v, acc[nt], 0, 0, 0);
      acc[nt] = __builtin_amdgcn_mfma_f32_32x32x16_bf16(al.v, bh.v, acc[nt], 0, 0, 0);
    }
  }
  // C/D: col = lane&31 (h), row = (r&3) + 8*(r>>2) + 4*(lane>>5)
#pragma unroll
  for (int nt = 0; nt < NT; nt++)
#pragma unroll
    for (int r = 0; r < 16; r++) {
      int n = nt * 32 + (r & 3) + 8 * (r >> 2) + 4 * lg;
      if (n < nrows)
        partial[((size_t)kb * nrows + n) * H + h0 + l31] = acc[nt][r];
    }
}

// ---------- combine KSM8 partials for M=8 GEMM: +bias, relu?, pack? ----------
__global__ __launch_bounds__(256) void k_combine8(const float* __restrict__ partial,
                                                  const float* __restrict__ bias,
                                                  float* __restrict__ Y,
                                                  unsigned short* __restrict__ phi,
                                                  unsigned short* __restrict__ plo,
                                                  int relu) {
  int t = blockIdx.x * 256 + threadIdx.x;   // 8192 float4s
  int row = t >> 10, c4 = (t & 1023) * 4;
  float4 s = *(const float4*)&bias[c4];
#pragma unroll
  for (int kb = 0; kb < KSM8; kb++) {
    float4 p = *(const float4*)&partial[((size_t)kb * 8 + row) * H + c4];
    s.x += p.x; s.y += p.y; s.z += p.z; s.w += p.w;
  }
  if (relu) {
    s.x = fmaxf(s.x, 0.f); s.y = fmaxf(s.y, 0.f);
    s.z = fmaxf(s.z, 0.f); s.w = fmaxf(s.w, 0.f);
  }
  if (Y) *(float4*)&Y[(size_t)row * H + c4] = s;
  if (phi) {
    float xs[4] = {s.x, s.y, s.z, s.w};
#pragma unroll
    for (int j = 0; j < 4; j++) {
      int k = c4 + j;
      int lane = row + ((k >> 3) & 1) * 32;
      size_t idx = ((size_t)(k >> 4) * 64 + lane) * 8 + (k & 7);
      unsigned short hb = f2bf(xs[j]);
      phi[idx] = hb;
      plo[idx] = f2bf(xs[j] - bf2f(hb));
    }
  }
}

// ---------- reduce npj k-split partials + bias ----------
__global__ __launch_bounds__(256) void k_npj_reduce(const float* __restrict__ npjp,
                                                    const float* __restrict__ bn,
                                                    float* __restrict__ npj, int ks) {
  int e4 = blockIdx.x * 256 + threadIdx.x;  // < NN*H/4
  int c4 = e4 & 1023;
  float4 s = ((const float4*)bn)[c4];
  for (int kb = 0; kb < ks; kb++) {
    float4 p = ((const float4*)npjp)[(size_t)kb * (NN * H / 4) + e4];
    s.x += p.x; s.y += p.y; s.z += p.z; s.w += p.w;
  }
  ((float4*)npj)[e4] = s;
}

// ---------- per-node rank keys: one block per node, all 8 batches ----------
__global__ __launch_bounds__(256) void k_sim(const float* __restrict__ qp,
                                             const float* __restrict__ npj,
                                             const int* __restrict__ batch,
                                             float* __restrict__ key) {
  const int n = blockIdx.x;
  const int tid = threadIdx.x, lane = tid & 63, wid = tid >> 6;
  __shared__ float red[4 * 9];
  __shared__ float fin[9];
  const float4* pv = (const float4*)(npj + (size_t)n * H);
  const float4* qv = (const float4*)qp;
  float acc[9];
#pragma unroll
  for (int j = 0; j < 9; j++) acc[j] = 0.f;
#pragma unroll
  for (int i = 0; i < 4; i++) {
    float4 p = pv[tid + i * 256];
    acc[0] = fmaf(p.x, p.x, fmaf(p.y, p.y, fmaf(p.z, p.z, fmaf(p.w, p.w, acc[0]))));
#pragma unroll
    for (int b = 0; b < 8; b++) {
      float4 q = qv[b * (H / 4) + tid + i * 256];
      acc[1 + b] = fmaf(p.x, q.x, fmaf(p.y, q.y, fmaf(p.z, q.z, fmaf(p.w, q.w, acc[1 + b]))));
    }
  }
#pragma unroll
  for (int j = 0; j < 9; j++)
#pragma unroll
    for (int off = 32; off > 0; off >>= 1) acc[j] += __shfl_xor(acc[j], off, 64);
  if (lane == 0)
#pragma unroll
    for (int j = 0; j < 9; j++) red[wid * 9 + j] = acc[j];
  __syncthreads();
  if (tid < 9) fin[tid] = red[0 * 9 + tid] + red[1 * 9 + tid] + red[2 * 9 + tid] + red[3 * 9 + tid];
  __syncthreads();
  if (tid < 8) {
    float r = rsqrtf(fmaxf(fin[0], 1e-30f));
    key[tid * NN + n] = (batch[n] == tid) ? fin[1 + tid] * r : -INFINITY;
  }
}

// ---------- per-batch: wave-parallel top3 + edge scan + list ----------
__global__ __launch_bounds__(256) void k_topedges(const float* __restrict__ key,
                                                  const int* __restrict__ edge,
                                                  const int* __restrict__ batch,
                                                  int* __restrict__ meta,
                                                  int* __restrict__ list) {
  const int b = blockIdx.x;
  const int tid = threadIdx.x, lane = tid & 63, wid = tid >> 6;
  __shared__ float key_s[256];
  __shared__ int starts_s[3], firsts_s[3];
  __shared__ float redv[4];
  __shared__ int redi[4];
  key_s[tid] = (tid < NN) ? key[b * NN + tid] : -INFINITY;
  if (tid < 3) firsts_s[tid] = EE;
  __syncthreads();
  for (int s = 0; s < 3; s++) {
    float v = key_s[tid];
    if ((s > 0 && tid == starts_s[0]) || (s > 1 && tid == starts_s[1])) v = -INFINITY;
    int idx = tid;
#pragma unroll
    for (int off = 32; off > 0; off >>= 1) {
      float ov = __shfl_xor(v, off, 64);
      int oi = __shfl_xor(idx, off, 64);
      if (ov > v || (ov == v && oi < idx)) { v = ov; idx = oi; }
    }
    if (lane == 0) { redv[wid] = v; redi[wid] = idx; }
    __syncthreads();
    if (tid == 0) {
      float bv = redv[0]; int bi = redi[0];
#pragma unroll
      for (int w = 1; w < 4; w++)
        if (redv[w] > bv || (redv[w] == bv && redi[w] < bi)) { bv = redv[w]; bi = redi[w]; }
      starts_s[s] = bi;
    }
    __syncthreads();
  }
  for (int e = tid; e < EE; e += 256) {
    int s = edge[e];
    int d = edge[EE + e];
    if (batch[d] == b) {
#pragma unroll
      for (int j = 0; j < 3; j++)
        if (s == starts_s[j]) atomicMin(&firsts_s[j], e);
    }
  }
  if (tid == 64) {
    int c = 0;
    for (int n = 0; n < NN; n++)
      if (batch[n] == b) list[b * NN + c++] = n;
    meta[b * 16 + 10] = c;
  }
  __syncthreads();
  if (tid == 0) {
    int c = 0;
#pragma unroll
    for (int j = 0; j < 3; j++) {
      int f = firsts_s[j];
      meta[b * 16 + j] = starts_s[j];
      meta[b * 16 + 3 + j] = f;
      meta[b * 16 + 6 + j] = edge[EE + (f < EE ? f : EE - 1)];
      c += (f < EE) ? 1 : 0;
    }
    meta[b * 16 + 9] = c;
  }
}

// ---------- agg (packed to frag) + fallback ----------
__global__ __launch_bounds__(256) void k_aggfall(const float* __restrict__ nf,
                                                 const float* __restrict__ npj,
                                                 const int* __restrict__ meta,
                                                 const int* __restrict__ list,
                                                 unsigned short* __restrict__ ahi,
                                                 unsigned short* __restrict__ alo,
                                                 float* __restrict__ fallb) {
  const int b = blockIdx.y;
  const int col = blockIdx.x * 256 + threadIdx.x;
  const int* m = meta + b * 16;
  const int cnt = m[9], cntn = m[10];
  float a = 0.f;
#pragma unroll
  for (int j = 0; j < 3; j++)
    if (m[3 + j] < EE)
      a += 0.5f * (nf[(size_t)m[j] * H + col] + nf[(size_t)m[6 + j] * H + col]);
  a /= (float)(cnt > 0 ? cnt : 1);
  // pack agg[b][col] into fragment order
  {
    int lane = b + ((col >> 3) & 1) * 32;
    size_t idx = ((size_t)(col >> 4) * 64 + lane) * 8 + (col & 7);
    unsigned short hb = f2bf(a);
    ahi[idx] = hb;
    alo[idx] = f2bf(a - bf2f(hb));
  }
  float f = 0.f;
  for (int i = 0; i < cntn; i++) f += npj[(size_t)list[b * NN + i] * H + col];
  fallb[(size_t)b * H + col] = f / (float)(cntn > 0 ? cntn : 1);
}

// ---------- select h vs fallback, LayerNorm, write out ----------
__global__ __launch_bounds__(256) void k_finalize(const float* __restrict__ hb,
                                                  const float* __restrict__ fallb,
                                                  const int* __restrict__ meta,
                                                  const float* __restrict__ g,
                                                  const float* __restrict__ beta,
                                                  float* __restrict__ out) {
  const int b = blockIdx.x;
  const int tid = threadIdx.x;
  const int wid = tid >> 6, lane = tid & 63;
  __shared__ float red[4];
  const float* src = (meta[b * 16 + 9] > 0) ? &hb[(size_t)b * H] : &fallb[(size_t)b * H];
  float v[16];
  float s = 0.f;
#pragma unroll
  for (int i = 0; i < 16; i++) {
    v[i] = src[tid + i * 256];
    s += v[i];
  }
#pragma unroll
  for (int off = 32; off > 0; off >>= 1) s += __shfl_xor(s, off, 64);
  if (lane == 0) red[wid] = s;
  __syncthreads();
  float mu = (red[0] + red[1] + red[2] + red[3]) * (1.f / H);
  float q = 0.f;
#pragma unroll
  for (int i = 0; i < 16; i++) {
    float d = v[i] - mu;
    q = fmaf(d, d, q);
  }
  __syncthreads();
#pragma unroll
  for (int off = 32; off > 0; off >>= 1) q += __shfl_xor(q, off, 64);
  if (lane == 0) red[wid] = q;
  __syncthreads();
  float var = (red[0] + red[1] + red[2] + red[3]) * (1.f / H);
  float inv = 1.f / sqrtf(var + 1e-5f);
#pragma unroll
  for (int i = 0; i < 16; i++) {
    int col = tid + i * 256;
    out[(size_t)b * H + col] = (v[i] - mu) * inv * g[col] + beta[col];
  }
}

extern "C" void kernel_launch(void* const* d_in, const int* in_sizes, int n_in,
                              void* d_out, int out_size, void* d_ws, size_t ws_size,
                              hipStream_t stream) {
  (void)in_sizes; (void)n_in; (void)out_size;
  const float* query = (const float*)d_in[0];
  const float* nf    = (const float*)d_in[1];
  const float* Wq = (const float*)d_in[2];
  const float* bq = (const float*)d_in[3];
  const float* Wn = (const float*)d_in[4];
  const float* bn = (const float*)d_in[5];
  const float* W1 = (const float*)d_in[6];
  const float* b1 = (const float*)d_in[7];
  const float* W2 = (const float*)d_in[8];
  const float* b2 = (const float*)d_in[9];
  const float* lng = (const float*)d_in[10];
  const float* lnb = (const float*)d_in[11];
  const int* edge  = (const int*)d_in[12];
  const int* batch = (const int*)d_in[13];

  char* ws = (char*)d_ws;
  unsigned short* qh  = (unsigned short*)(ws + OFF_QH);
  unsigned short* ql  = (unsigned short*)(ws + OFF_QL);
  unsigned short* ah  = (unsigned short*)(ws + OFF_AH);
  unsigned short* al  = (unsigned short*)(ws + OFF_AL);
  unsigned short* th  = (unsigned short*)(ws + OFF_TH);
  unsigned short* tl  = (unsigned short*)(ws + OFF_TL);
  unsigned short* nfh = (unsigned short*)(ws + OFF_NFH);
  unsigned short* nfl = (unsigned short*)(ws + OFF_NFL);
  float* qp    = (float*)(ws + OFF_QP);
  float* hbuf  = (float*)(ws + OFF_HB);
  float* fallb = (float*)(ws + OFF_FB);
  float* keyb  = (float*)(ws + OFF_KEY);
  int*   meta  = (int*)(ws + OFF_META);
  int*   list  = (int*)(ws + OFF_LIST);
  float* p8    = (float*)(ws + OFF_SH);   // KSM8*8*H*4 = 4 MB
  float* npjp  = (float*)(ws + OFF_SH);   // ks*NN*H*4 (reused after p8 dead)
  // npj f32 lives right after the largest shared use? -> keep separate fixed slot
  // (placed after SH sizing below)

  size_t per = (size_t)NN * H * 4u;       // 3,276,800
  int ks = 4;
  if (ws_size >= (size_t)OFF_SH + 16 * per + per) ks = 16;
  else if (ws_size >= (size_t)OFF_SH + 8 * per + per) ks = 8;
  int nk = KT16 / ks;
  size_t shmax = (size_t)ks * per;
  if (shmax < 4194304u) shmax = 4194304u;
  float* npj = (float*)(ws + OFF_SH + shmax);   // NN*H*4 after shared region

  // --- query projection ---
  k_pack8<<<dim3(64), dim3(256), 0, stream>>>(query, qh, ql);
  k_mfma32<1, 4><<<dim3(HT32 * KSM8 / 4), dim3(256), 0, stream>>>(qh, ql, Wq, p8, KT16 / KSM8, 8);
  k_combine8<<<dim3(32), dim3(256), 0, stream>>>(p8, bq, qp, nullptr, nullptr, 0);
  // --- node projection ---
  k_pack_nf<<<dim3(KT16 * NT_NF * 64 / 256), dim3(256), 0, stream>>>(nf, nfh, nfl);
  k_mfma32<NT_NF, 2><<<dim3(HT32 * ks / 4), dim3(256), 0, stream>>>(nfh, nfl, Wn, npjp, nk, NN);
  k_npj_reduce<<<dim3(NN * H / 4 / 256), dim3(256), 0, stream>>>(npjp, bn, npj, ks);
  // --- selection ---
  k_sim<<<dim3(NN), dim3(256), 0, stream>>>(qp, npj, batch, keyb);
  k_topedges<<<dim3(BB), dim3(256), 0, stream>>>(keyb, edge, batch, meta, list);
  k_aggfall<<<dim3(16, BB), dim3(256), 0, stream>>>(nf, npj, meta, list, ah, al, fallb);
  // --- MLP ---
  k_mfma32<1, 4><<<dim3(HT32 * KSM8 / 4), dim3(256), 0, stream>>>(ah, al, W1, p8, KT16 / KSM8, 8);
  k_combine8<<<dim3(32), dim3(256), 0, stream>>>(p8, b1, nullptr, th, tl, 1);
  k_mfma32<1, 4><<<dim3(HT32 * KSM8 / 4), dim3(256), 0, stream>>>(th, tl, W2, p8, KT16 / KSM8, 8);
  k_combine8<<<dim3(32), dim3(256), 0, stream>>>(p8, b2, hbuf, nullptr, nullptr, 0);
  // --- layernorm ---
  k_finalize<<<dim3(BB), dim3(256), 0, stream>>>(hbuf, fallb, meta, lng, lnb, (float*)d_out);
}